// Round 1
// baseline (2471.650 us; speedup 1.0000x reference)
//
#include <hip/hip_runtime.h>

#define N_USERS  100000
#define N_ITEMS  100000
#define N_NODES  200000
#define EMBED    64
#define NB       3
#define N_EDGESC 2000000
#define BATCH    4096

// ---------------------------------------------------------------- degree count
__global__ __launch_bounds__(256) void deg_kernel(const int* __restrict__ edges,
                                                  int* __restrict__ deg) {
    int idx = blockIdx.x * 256 + threadIdx.x;
    if (idx >= NB * N_EDGESC) return;
    int bi = idx / N_EDGESC;
    int e  = idx - bi * N_EDGESC;
    int c  = edges[((size_t)bi * 2 + 1) * N_EDGESC + e];  // col array of behavior bi
    atomicAdd(&deg[bi * N_NODES + c], 1);
}

// ---------------------------------------------------------------- dinv = rsqrt(deg)
__global__ __launch_bounds__(256) void dinv_kernel(const int* __restrict__ deg,
                                                   float* __restrict__ dinv) {
    int idx = blockIdx.x * 256 + threadIdx.x;
    if (idx >= NB * N_NODES) return;
    int d = deg[idx];
    dinv[idx] = (d > 0) ? rsqrtf((float)d) : 0.0f;
}

// ---------------------------------------------------------------- x = A(200000x64) @ W(64x64)
// lane j holds W[:, j] in 64 VGPRs; each wave streams rows, row data via
// wave-uniform float4 broadcast loads (1 transaction each).
__global__ __launch_bounds__(256) void gemm_kernel(const float* __restrict__ A,
                                                   const float* __restrict__ W,
                                                   float* __restrict__ X) {
    int j     = threadIdx.x & 63;
    int wave  = (blockIdx.x * 256 + threadIdx.x) >> 6;
    int nwave = gridDim.x * 4;
    float w[64];
#pragma unroll
    for (int k = 0; k < 64; ++k) w[k] = W[k * 64 + j];
    for (int r = wave; r < N_NODES; r += nwave) {
        const float4* a4 = (const float4*)(A + (size_t)r * 64);
        float acc = 0.0f;
#pragma unroll
        for (int k4 = 0; k4 < 16; ++k4) {
            float4 a = a4[k4];
            acc += a.x * w[4 * k4 + 0] + a.y * w[4 * k4 + 1] +
                   a.z * w[4 * k4 + 2] + a.w * w[4 * k4 + 3];
        }
        X[(size_t)r * 64 + j] = acc;
    }
}

// ---------------------------------------------------------------- edge scatter (atomic)
// one wave per edge: gather 256B of x[row], atomic-add 256B into out[col]
__global__ __launch_bounds__(256) void scatter_kernel(const int* __restrict__ rowi,
                                                      const int* __restrict__ coli,
                                                      const float* __restrict__ dinv,
                                                      const float* __restrict__ x,
                                                      float* __restrict__ out) {
    int gid  = blockIdx.x * 256 + threadIdx.x;
    int e    = gid >> 6;
    int lane = threadIdx.x & 63;
    if (e >= N_EDGESC) return;
    int   r    = rowi[e];
    int   c    = coli[e];
    float norm = dinv[r] * dinv[c];
    float v    = x[(size_t)r * 64 + lane] * norm;
    unsafeAtomicAdd(&out[(size_t)c * 64 + lane], v);
}

// ---------------------------------------------------------------- l2-normalize + residual
__global__ __launch_bounds__(256) void norm_update(const float* __restrict__ conv,
                                                   const float* __restrict__ bias,
                                                   float* __restrict__ total) {
    int gid  = blockIdx.x * 256 + threadIdx.x;
    int n    = gid >> 6;
    int lane = threadIdx.x & 63;
    if (n >= N_NODES) return;
    float v = conv[(size_t)n * 64 + lane] + bias[lane];
    float s = v * v;
#pragma unroll
    for (int off = 32; off; off >>= 1) s += __shfl_xor(s, off, 64);
    float nrm = sqrtf(s);
    float inv = 1.0f / fmaxf(nrm, 1e-12f);
    size_t idx = (size_t)n * 64 + lane;
    total[idx] = total[idx] + v * inv;
}

// ---------------------------------------------------------------- BPR loss for behavior bi
__global__ __launch_bounds__(256) void bpr_kernel(const float* __restrict__ total,
                                                  const int* __restrict__ batch,
                                                  int bi, float* __restrict__ loss) {
    int gid  = blockIdx.x * 256 + threadIdx.x;
    int b    = gid >> 6;
    int lane = threadIdx.x & 63;
    if (b >= BATCH) return;
    int u  = batch[((size_t)b * NB + bi) * 3 + 0];
    int i0 = batch[((size_t)b * NB + bi) * 3 + 1];
    int i1 = batch[((size_t)b * NB + bi) * 3 + 2];
    float uf = total[(size_t)u * 64 + lane];
    float f0 = total[(size_t)(N_USERS + i0) * 64 + lane];
    float f1 = total[(size_t)(N_USERS + i1) * 64 + lane];
    float d  = uf * (f0 - f1);
#pragma unroll
    for (int off = 32; off; off >>= 1) d += __shfl_xor(d, off, 64);
    if (lane == 0) {
        // -log_sigmoid(d) = softplus(-d), numerically stable both sides
        float sp = (d > 0.0f) ? log1pf(expf(-d)) : (-d + log1pf(expf(d)));
        unsafeAtomicAdd(loss, sp * (1.0f / BATCH));
    }
}

// ---------------------------------------------------------------- embedding L2 reg
__global__ __launch_bounds__(256) void reg_kernel(const float* __restrict__ ue,
                                                  const float* __restrict__ ie,
                                                  float* __restrict__ loss) {
    const size_t n4 = (size_t)N_USERS * EMBED / 4;  // same count for items
    size_t tid    = (size_t)blockIdx.x * 256 + threadIdx.x;
    size_t stride = (size_t)gridDim.x * 256;
    const float4* u4 = (const float4*)ue;
    const float4* i4 = (const float4*)ie;
    float s = 0.0f;
    for (size_t i = tid; i < n4; i += stride) {
        float4 a = u4[i];
        s += a.x * a.x + a.y * a.y + a.z * a.z + a.w * a.w;
        float4 b = i4[i];
        s += b.x * b.x + b.y * b.y + b.z * b.z + b.w * b.w;
    }
#pragma unroll
    for (int off = 32; off; off >>= 1) s += __shfl_xor(s, off, 64);
    if ((threadIdx.x & 63) == 0)
        unsafeAtomicAdd(loss, s * (0.5f * 0.0001f / (float)BATCH));
}

// ---------------------------------------------------------------- final scalar write
__global__ void final_write(const float* __restrict__ loss, float* __restrict__ out) {
    out[0] = loss[0];
}

extern "C" void kernel_launch(void* const* d_in, const int* in_sizes, int n_in,
                              void* d_out, int out_size, void* d_ws, size_t ws_size,
                              hipStream_t stream) {
    const float* user_emb = (const float*)d_in[0];
    const float* item_emb = (const float*)d_in[1];
    const float* gcn_w    = (const float*)d_in[2];
    const float* gcn_b    = (const float*)d_in[3];
    const int*   edges    = (const int*)d_in[4];   // (3, 2, 2M) int32
    const int*   batch    = (const int*)d_in[5];   // (4096, 3, 3) int32
    float*       out      = (float*)d_out;

    const size_t NODE_F = (size_t)N_NODES * EMBED;        // 12.8M floats
    float* total = (float*)d_ws;                          //  51.2 MB
    float* xbuf  = total + NODE_F;                        //  51.2 MB
    float* convb = xbuf + NODE_F;                         //  51.2 MB
    float* dinv  = convb + NODE_F;                        //   2.4 MB
    int*   deg   = (int*)(dinv + (size_t)NB * N_NODES);   //   2.4 MB
    float* loss  = (float*)(deg + (size_t)NB * N_NODES);  //   4 B

    hipMemsetAsync(loss, 0, sizeof(float), stream);
    hipMemsetAsync(deg, 0, (size_t)NB * N_NODES * sizeof(int), stream);
    hipMemcpyAsync(total, user_emb, (size_t)N_USERS * EMBED * sizeof(float),
                   hipMemcpyDeviceToDevice, stream);
    hipMemcpyAsync(total + (size_t)N_USERS * EMBED, item_emb,
                   (size_t)N_ITEMS * EMBED * sizeof(float),
                   hipMemcpyDeviceToDevice, stream);

    deg_kernel<<<(NB * N_EDGESC + 255) / 256, 256, 0, stream>>>(edges, deg);
    dinv_kernel<<<(NB * N_NODES + 255) / 256, 256, 0, stream>>>(deg, dinv);
    reg_kernel<<<2048, 256, 0, stream>>>(user_emb, item_emb, loss);

    for (int bi = 0; bi < NB; ++bi) {
        gemm_kernel<<<2048, 256, 0, stream>>>(
            total, gcn_w + (size_t)bi * EMBED * EMBED, xbuf);
        hipMemsetAsync(convb, 0, NODE_F * sizeof(float), stream);
        scatter_kernel<<<((size_t)N_EDGESC * EMBED) / 256, 256, 0, stream>>>(
            edges + (size_t)bi * 2 * N_EDGESC,          // row
            edges + ((size_t)bi * 2 + 1) * N_EDGESC,    // col
            dinv + (size_t)bi * N_NODES, xbuf, convb);
        norm_update<<<(N_NODES * EMBED) / 256, 256, 0, stream>>>(
            convb, gcn_b + bi * EMBED, total);
        bpr_kernel<<<(BATCH * EMBED) / 256, 256, 0, stream>>>(total, batch, bi, loss);
    }
    final_write<<<1, 1, 0, stream>>>(loss, out);
}

// Round 2
// 1880.624 us; speedup vs baseline: 1.3143x; 1.3143x over previous
//
#include <hip/hip_runtime.h>

#define N_USERS  100000
#define N_ITEMS  100000
#define N_NODES  200000
#define EMBED    64
#define NB       3
#define N_EDGESC 2000000
#define BATCH    4096
#define M_SEG    (NB * N_NODES)          // 600000 segments (flat over behaviors)
#define SCAN_BLOCKS ((M_SEG + 255) / 256)

// ---------------------------------------------------------------- degree count
__global__ __launch_bounds__(256) void deg_kernel(const int* __restrict__ edges,
                                                  int* __restrict__ deg) {
    int idx = blockIdx.x * 256 + threadIdx.x;
    if (idx >= NB * N_EDGESC) return;
    int bi = idx / N_EDGESC;
    int e  = idx - bi * N_EDGESC;
    int c  = edges[((size_t)bi * 2 + 1) * N_EDGESC + e];
    atomicAdd(&deg[bi * N_NODES + c], 1);
}

// ---------------------------------------------------------------- dinv = rsqrt(deg)
__global__ __launch_bounds__(256) void dinv_kernel(const int* __restrict__ deg,
                                                   float* __restrict__ dinv) {
    int idx = blockIdx.x * 256 + threadIdx.x;
    if (idx >= M_SEG) return;
    int d = deg[idx];
    dinv[idx] = (d > 0) ? rsqrtf((float)d) : 0.0f;
}

// ---------------------------------------------------------------- scan phase 1
// per-256-block exclusive scan + block sums
__global__ __launch_bounds__(256) void scan1(const int* __restrict__ deg,
                                             int* __restrict__ excl,
                                             int* __restrict__ bsum) {
    __shared__ int s[256];
    int gid = blockIdx.x * 256 + threadIdx.x;
    int v = (gid < M_SEG) ? deg[gid] : 0;
    s[threadIdx.x] = v;
    __syncthreads();
    for (int off = 1; off < 256; off <<= 1) {
        int t = (threadIdx.x >= off) ? s[threadIdx.x - off] : 0;
        __syncthreads();
        s[threadIdx.x] += t;
        __syncthreads();
    }
    if (gid < M_SEG) excl[gid] = s[threadIdx.x] - v;
    if (threadIdx.x == 255) bsum[blockIdx.x] = s[255];
}

// ---------------------------------------------------------------- scan phase 2
// exclusive scan of block sums, single block
__global__ __launch_bounds__(256) void scan2(int* __restrict__ bsum, int n) {
    __shared__ int s[256];
    int tid = threadIdx.x;
    int chunk = (n + 255) / 256;
    int lo = tid * chunk;
    int hi = lo + chunk; if (hi > n) hi = n;
    int sum = 0;
    for (int i = lo; i < hi; ++i) sum += bsum[i];
    s[tid] = sum;
    __syncthreads();
    for (int off = 1; off < 256; off <<= 1) {
        int t = (tid >= off) ? s[tid - off] : 0;
        __syncthreads();
        s[tid] += t;
        __syncthreads();
    }
    int acc = s[tid] - sum;  // exclusive base for this chunk
    for (int i = lo; i < hi; ++i) { int t = bsum[i]; bsum[i] = acc; acc += t; }
}

// ---------------------------------------------------------------- scan phase 3
// offsets = excl + scanned block sums (writes into both start & cursor copies)
__global__ __launch_bounds__(256) void scan3(const int* __restrict__ excl,
                                             const int* __restrict__ bsum,
                                             int* __restrict__ start,
                                             int* __restrict__ cursor) {
    int gid = blockIdx.x * 256 + threadIdx.x;
    if (gid >= M_SEG) return;
    int v = excl[gid] + bsum[blockIdx.x];
    start[gid]  = v;
    cursor[gid] = v;
}

// ---------------------------------------------------------------- edge fill (counting sort by col)
__global__ __launch_bounds__(256) void fill_kernel(const int* __restrict__ edges,
                                                   int* __restrict__ cursor,
                                                   int* __restrict__ srow) {
    int idx = blockIdx.x * 256 + threadIdx.x;
    if (idx >= NB * N_EDGESC) return;
    int bi = idx / N_EDGESC;
    int e  = idx - bi * N_EDGESC;
    int r = edges[((size_t)bi * 2 + 0) * N_EDGESC + e];
    int c = edges[((size_t)bi * 2 + 1) * N_EDGESC + e];
    int pos = atomicAdd(&cursor[bi * N_NODES + c], 1);
    srow[pos] = r;
}

// ---------------------------------------------------------------- x = A(200000x64) @ W(64x64)
__global__ __launch_bounds__(256) void gemm_kernel(const float* __restrict__ A,
                                                   const float* __restrict__ W,
                                                   float* __restrict__ X) {
    int j     = threadIdx.x & 63;
    int wave  = (blockIdx.x * 256 + threadIdx.x) >> 6;
    int nwave = gridDim.x * 4;
    float w[64];
#pragma unroll
    for (int k = 0; k < 64; ++k) w[k] = W[k * 64 + j];
    for (int r = wave; r < N_NODES; r += nwave) {
        const float4* a4 = (const float4*)(A + (size_t)r * 64);
        float acc = 0.0f;
#pragma unroll
        for (int k4 = 0; k4 < 16; ++k4) {
            float4 a = a4[k4];
            acc += a.x * w[4 * k4 + 0] + a.y * w[4 * k4 + 1] +
                   a.z * w[4 * k4 + 2] + a.w * w[4 * k4 + 3];
        }
        X[(size_t)r * 64 + j] = acc;
    }
}

// ---------------------------------------------------------------- gather-accumulate + bias + l2norm + residual
// one wave per destination node: sum its sorted segment, then fused epilogue
__global__ __launch_bounds__(256) void gather_update(const int* __restrict__ srow,
                                                     const int* __restrict__ start,
                                                     const int* __restrict__ deg,
                                                     const float* __restrict__ dinv,
                                                     const float* __restrict__ x,
                                                     const float* __restrict__ bias,
                                                     float* __restrict__ total,
                                                     int base /* = bi*N_NODES */) {
    int gid  = blockIdx.x * 256 + threadIdx.x;
    int c    = gid >> 6;
    int lane = threadIdx.x & 63;
    if (c >= N_NODES) return;
    int   s  = start[base + c];
    int   d  = deg[base + c];
    float dc = dinv[base + c];
    float acc = 0.0f;
    int e = s, end = s + d;
    // 4-wide unroll for memory-level parallelism
    for (; e + 4 <= end; e += 4) {
        int r0 = srow[e], r1 = srow[e + 1], r2 = srow[e + 2], r3 = srow[e + 3];
        float n0 = dinv[base + r0], n1 = dinv[base + r1];
        float n2 = dinv[base + r2], n3 = dinv[base + r3];
        float v0 = x[(size_t)r0 * 64 + lane];
        float v1 = x[(size_t)r1 * 64 + lane];
        float v2 = x[(size_t)r2 * 64 + lane];
        float v3 = x[(size_t)r3 * 64 + lane];
        acc += n0 * v0 + n1 * v1 + n2 * v2 + n3 * v3;
    }
    for (; e < end; ++e) {
        int r = srow[e];
        acc += dinv[base + r] * x[(size_t)r * 64 + lane];
    }
    float v = acc * dc + bias[lane];
    float sq = v * v;
#pragma unroll
    for (int off = 32; off; off >>= 1) sq += __shfl_xor(sq, off, 64);
    float nrm = sqrtf(sq);
    float inv = 1.0f / fmaxf(nrm, 1e-12f);
    size_t idx = (size_t)c * 64 + lane;
    total[idx] = total[idx] + v * inv;
}

// ---------------------------------------------------------------- BPR loss for behavior bi
__global__ __launch_bounds__(256) void bpr_kernel(const float* __restrict__ total,
                                                  const int* __restrict__ batch,
                                                  int bi, float* __restrict__ loss) {
    int gid  = blockIdx.x * 256 + threadIdx.x;
    int b    = gid >> 6;
    int lane = threadIdx.x & 63;
    if (b >= BATCH) return;
    int u  = batch[((size_t)b * NB + bi) * 3 + 0];
    int i0 = batch[((size_t)b * NB + bi) * 3 + 1];
    int i1 = batch[((size_t)b * NB + bi) * 3 + 2];
    float uf = total[(size_t)u * 64 + lane];
    float f0 = total[(size_t)(N_USERS + i0) * 64 + lane];
    float f1 = total[(size_t)(N_USERS + i1) * 64 + lane];
    float d  = uf * (f0 - f1);
#pragma unroll
    for (int off = 32; off; off >>= 1) d += __shfl_xor(d, off, 64);
    if (lane == 0) {
        float sp = (d > 0.0f) ? log1pf(expf(-d)) : (-d + log1pf(expf(d)));
        unsafeAtomicAdd(loss, sp * (1.0f / BATCH));
    }
}

// ---------------------------------------------------------------- embedding L2 reg
__global__ __launch_bounds__(256) void reg_kernel(const float* __restrict__ ue,
                                                  const float* __restrict__ ie,
                                                  float* __restrict__ loss) {
    const size_t n4 = (size_t)N_USERS * EMBED / 4;
    size_t tid    = (size_t)blockIdx.x * 256 + threadIdx.x;
    size_t stride = (size_t)gridDim.x * 256;
    const float4* u4 = (const float4*)ue;
    const float4* i4 = (const float4*)ie;
    float s = 0.0f;
    for (size_t i = tid; i < n4; i += stride) {
        float4 a = u4[i];
        s += a.x * a.x + a.y * a.y + a.z * a.z + a.w * a.w;
        float4 b = i4[i];
        s += b.x * b.x + b.y * b.y + b.z * b.z + b.w * b.w;
    }
#pragma unroll
    for (int off = 32; off; off >>= 1) s += __shfl_xor(s, off, 64);
    if ((threadIdx.x & 63) == 0)
        unsafeAtomicAdd(loss, s * (0.5f * 0.0001f / (float)BATCH));
}

// ---------------------------------------------------------------- final scalar write
__global__ void final_write(const float* __restrict__ loss, float* __restrict__ out) {
    out[0] = loss[0];
}

extern "C" void kernel_launch(void* const* d_in, const int* in_sizes, int n_in,
                              void* d_out, int out_size, void* d_ws, size_t ws_size,
                              hipStream_t stream) {
    const float* user_emb = (const float*)d_in[0];
    const float* item_emb = (const float*)d_in[1];
    const float* gcn_w    = (const float*)d_in[2];
    const float* gcn_b    = (const float*)d_in[3];
    const int*   edges    = (const int*)d_in[4];   // (3, 2, 2M) int32
    const int*   batch    = (const int*)d_in[5];   // (4096, 3, 3) int32
    float*       out      = (float*)d_out;

    const size_t NODE_F = (size_t)N_NODES * EMBED;            // 12.8M floats
    float* total  = (float*)d_ws;                             // 51.2 MB
    float* xbuf   = total + NODE_F;                           // 51.2 MB
    float* dinv   = xbuf + NODE_F;                            //  2.4 MB
    int*   deg    = (int*)(dinv + M_SEG);                     //  2.4 MB
    int*   excl   = deg + M_SEG;                              //  2.4 MB
    int*   startv = excl + M_SEG;                             //  2.4 MB
    int*   cursor = startv + M_SEG;                           //  2.4 MB
    int*   bsum   = cursor + M_SEG;                           //  16 KB
    int*   srow   = bsum + 4096;                              //  24 MB
    float* loss   = (float*)(srow + (size_t)NB * N_EDGESC);   //   4 B

    hipMemsetAsync(loss, 0, sizeof(float), stream);
    hipMemsetAsync(deg, 0, (size_t)M_SEG * sizeof(int), stream);
    hipMemcpyAsync(total, user_emb, (size_t)N_USERS * EMBED * sizeof(float),
                   hipMemcpyDeviceToDevice, stream);
    hipMemcpyAsync(total + (size_t)N_USERS * EMBED, item_emb,
                   (size_t)N_ITEMS * EMBED * sizeof(float),
                   hipMemcpyDeviceToDevice, stream);

    // edge preprocessing (depends only on inputs)
    deg_kernel<<<(NB * N_EDGESC + 255) / 256, 256, 0, stream>>>(edges, deg);
    dinv_kernel<<<(M_SEG + 255) / 256, 256, 0, stream>>>(deg, dinv);
    scan1<<<SCAN_BLOCKS, 256, 0, stream>>>(deg, excl, bsum);
    scan2<<<1, 256, 0, stream>>>(bsum, SCAN_BLOCKS);
    scan3<<<SCAN_BLOCKS, 256, 0, stream>>>(excl, bsum, startv, cursor);
    fill_kernel<<<(NB * N_EDGESC + 255) / 256, 256, 0, stream>>>(edges, cursor, srow);

    reg_kernel<<<2048, 256, 0, stream>>>(user_emb, item_emb, loss);

    for (int bi = 0; bi < NB; ++bi) {
        gemm_kernel<<<2048, 256, 0, stream>>>(
            total, gcn_w + (size_t)bi * EMBED * EMBED, xbuf);
        gather_update<<<(N_NODES * 64 + 255) / 256, 256, 0, stream>>>(
            srow, startv, deg, dinv, xbuf, gcn_b + bi * EMBED, total, bi * N_NODES);
        bpr_kernel<<<(BATCH * 64 + 255) / 256, 256, 0, stream>>>(total, batch, bi, loss);
    }
    final_write<<<1, 1, 0, stream>>>(loss, out);
}

// Round 3
// 1378.629 us; speedup vs baseline: 1.7928x; 1.3641x over previous
//
#include <hip/hip_runtime.h>

#define N_USERS  100000
#define N_ITEMS  100000
#define N_NODES  200000
#define EMBED    64
#define NB       3
#define N_EDGESC 2000000
#define BATCH    4096
#define M_SEG    (NB * N_NODES)          // 600000 segments (flat over behaviors)
#define SCAN_BLOCKS ((M_SEG + 255) / 256)

// ---------------------------------------------------------------- degree count
__global__ __launch_bounds__(256) void deg_kernel(const int* __restrict__ edges,
                                                  int* __restrict__ deg) {
    int idx = blockIdx.x * 256 + threadIdx.x;
    if (idx >= NB * N_EDGESC) return;
    int bi = idx / N_EDGESC;
    int e  = idx - bi * N_EDGESC;
    int c  = edges[((size_t)bi * 2 + 1) * N_EDGESC + e];
    atomicAdd(&deg[bi * N_NODES + c], 1);
}

// ---------------------------------------------------------------- dinv = rsqrt(deg)
__global__ __launch_bounds__(256) void dinv_kernel(const int* __restrict__ deg,
                                                   float* __restrict__ dinv) {
    int idx = blockIdx.x * 256 + threadIdx.x;
    if (idx >= M_SEG) return;
    int d = deg[idx];
    dinv[idx] = (d > 0) ? rsqrtf((float)d) : 0.0f;
}

// ---------------------------------------------------------------- scan phase 1
__global__ __launch_bounds__(256) void scan1(const int* __restrict__ deg,
                                             int* __restrict__ excl,
                                             int* __restrict__ bsum) {
    __shared__ int s[256];
    int gid = blockIdx.x * 256 + threadIdx.x;
    int v = (gid < M_SEG) ? deg[gid] : 0;
    s[threadIdx.x] = v;
    __syncthreads();
    for (int off = 1; off < 256; off <<= 1) {
        int t = (threadIdx.x >= off) ? s[threadIdx.x - off] : 0;
        __syncthreads();
        s[threadIdx.x] += t;
        __syncthreads();
    }
    if (gid < M_SEG) excl[gid] = s[threadIdx.x] - v;
    if (threadIdx.x == 255) bsum[blockIdx.x] = s[255];
}

// ---------------------------------------------------------------- scan phase 2
__global__ __launch_bounds__(256) void scan2(int* __restrict__ bsum, int n) {
    __shared__ int s[256];
    int tid = threadIdx.x;
    int chunk = (n + 255) / 256;
    int lo = tid * chunk;
    int hi = lo + chunk; if (hi > n) hi = n;
    int sum = 0;
    for (int i = lo; i < hi; ++i) sum += bsum[i];
    s[tid] = sum;
    __syncthreads();
    for (int off = 1; off < 256; off <<= 1) {
        int t = (tid >= off) ? s[tid - off] : 0;
        __syncthreads();
        s[tid] += t;
        __syncthreads();
    }
    int acc = s[tid] - sum;
    for (int i = lo; i < hi; ++i) { int t = bsum[i]; bsum[i] = acc; acc += t; }
}

// ---------------------------------------------------------------- scan phase 3
__global__ __launch_bounds__(256) void scan3(const int* __restrict__ excl,
                                             const int* __restrict__ bsum,
                                             int* __restrict__ start,
                                             int* __restrict__ cursor) {
    int gid = blockIdx.x * 256 + threadIdx.x;
    if (gid >= M_SEG) return;
    int v = excl[gid] + bsum[blockIdx.x];
    start[gid]  = v;
    cursor[gid] = v;
}

// ---------------------------------------------------------------- edge fill, XCD-partitioned
// 8 block-groups (blockIdx&7); group p sweeps all edges, writes only cols in
// its 1/8 range -> per-group write region is a ~1MB contiguous slice (L2-resident).
__global__ __launch_bounds__(256) void fill_kernel(const int* __restrict__ edges,
                                                   int* __restrict__ cursor,
                                                   int* __restrict__ srow) {
    const int part = blockIdx.x & 7;
    const int lo   = part * (N_NODES / 8);
    const int hi   = lo + (N_NODES / 8);
    int idx    = (blockIdx.x >> 3) * 256 + threadIdx.x;
    int stride = (gridDim.x >> 3) * 256;
    for (; idx < NB * N_EDGESC; idx += stride) {
        int bi = idx / N_EDGESC;
        int e  = idx - bi * N_EDGESC;
        int c  = edges[((size_t)bi * 2 + 1) * N_EDGESC + e];
        if (c >= lo && c < hi) {
            int r = edges[((size_t)bi * 2 + 0) * N_EDGESC + e];
            int pos = atomicAdd(&cursor[bi * N_NODES + c], 1);
            srow[pos] = r;
        }
    }
}

// ---------------------------------------------------------------- fused conv:
// gather-accumulate raw total rows + @W (LDS) + bias + l2norm + residual.
// one wave per destination node; W linearity: segsum(n*(xW)) = segsum(n*x)@W
__global__ __launch_bounds__(256) void conv_kernel(const int* __restrict__ srow,
                                                   const int* __restrict__ start,
                                                   const int* __restrict__ deg,
                                                   const float* __restrict__ dinv,
                                                   const float* __restrict__ tin,
                                                   const float* __restrict__ W,
                                                   const float* __restrict__ bias,
                                                   float* __restrict__ tout,
                                                   int base /* bi*N_NODES */) {
    __shared__ float sW[64 * 64];
    __shared__ float sAcc[4][64];
    for (int i = threadIdx.x; i < 1024; i += 256)
        ((float4*)sW)[i] = ((const float4*)W)[i];
    __syncthreads();

    int gid  = blockIdx.x * 256 + threadIdx.x;   // grid exactly N_NODES*64
    int c    = gid >> 6;
    int wv   = threadIdx.x >> 6;
    int lane = threadIdx.x & 63;

    int   s  = start[base + c];
    int   d  = deg[base + c];
    float dc = dinv[base + c];
    float acc = 0.0f;
    int e = s, end = s + d;
    for (; e + 4 <= end; e += 4) {
        int r0 = srow[e], r1 = srow[e + 1], r2 = srow[e + 2], r3 = srow[e + 3];
        float n0 = dinv[base + r0], n1 = dinv[base + r1];
        float n2 = dinv[base + r2], n3 = dinv[base + r3];
        float v0 = tin[(size_t)r0 * 64 + lane];
        float v1 = tin[(size_t)r1 * 64 + lane];
        float v2 = tin[(size_t)r2 * 64 + lane];
        float v3 = tin[(size_t)r3 * 64 + lane];
        acc += n0 * v0 + n1 * v1 + n2 * v2 + n3 * v3;
    }
    for (; e < end; ++e) {
        int r = srow[e];
        acc += dinv[base + r] * tin[(size_t)r * 64 + lane];
    }
    // exchange acc across the wave via LDS, apply W column-wise
    sAcc[wv][lane] = acc;
    float v = 0.0f;
#pragma unroll
    for (int k = 0; k < 64; ++k)
        v += sAcc[wv][k] * sW[k * 64 + lane];    // broadcast + conflict-free
    v = v * dc + bias[lane];
    float sq = v * v;
#pragma unroll
    for (int off = 32; off; off >>= 1) sq += __shfl_xor(sq, off, 64);
    float inv = 1.0f / fmaxf(sqrtf(sq), 1e-12f);
    size_t idx = (size_t)c * 64 + lane;
    tout[idx] = tin[idx] + v * inv;
}

// ---------------------------------------------------------------- BPR loss
__global__ __launch_bounds__(256) void bpr_kernel(const float* __restrict__ total,
                                                  const int* __restrict__ batch,
                                                  int bi, float* __restrict__ loss) {
    int gid  = blockIdx.x * 256 + threadIdx.x;
    int b    = gid >> 6;
    int lane = threadIdx.x & 63;
    if (b >= BATCH) return;
    int u  = batch[((size_t)b * NB + bi) * 3 + 0];
    int i0 = batch[((size_t)b * NB + bi) * 3 + 1];
    int i1 = batch[((size_t)b * NB + bi) * 3 + 2];
    float uf = total[(size_t)u * 64 + lane];
    float f0 = total[(size_t)(N_USERS + i0) * 64 + lane];
    float f1 = total[(size_t)(N_USERS + i1) * 64 + lane];
    float d  = uf * (f0 - f1);
#pragma unroll
    for (int off = 32; off; off >>= 1) d += __shfl_xor(d, off, 64);
    if (lane == 0) {
        float sp = (d > 0.0f) ? log1pf(expf(-d)) : (-d + log1pf(expf(d)));
        unsafeAtomicAdd(loss, sp * (1.0f / BATCH));
    }
}

// ---------------------------------------------------------------- embedding L2 reg
__global__ __launch_bounds__(256) void reg_kernel(const float* __restrict__ ue,
                                                  const float* __restrict__ ie,
                                                  float* __restrict__ loss) {
    const size_t n4 = (size_t)N_USERS * EMBED / 4;
    size_t tid    = (size_t)blockIdx.x * 256 + threadIdx.x;
    size_t stride = (size_t)gridDim.x * 256;
    const float4* u4 = (const float4*)ue;
    const float4* i4 = (const float4*)ie;
    float s = 0.0f;
    for (size_t i = tid; i < n4; i += stride) {
        float4 a = u4[i];
        s += a.x * a.x + a.y * a.y + a.z * a.z + a.w * a.w;
        float4 b = i4[i];
        s += b.x * b.x + b.y * b.y + b.z * b.z + b.w * b.w;
    }
#pragma unroll
    for (int off = 32; off; off >>= 1) s += __shfl_xor(s, off, 64);
    if ((threadIdx.x & 63) == 0)
        unsafeAtomicAdd(loss, s * (0.5f * 0.0001f / (float)BATCH));
}

// ---------------------------------------------------------------- final scalar write
__global__ void final_write(const float* __restrict__ loss, float* __restrict__ out) {
    out[0] = loss[0];
}

extern "C" void kernel_launch(void* const* d_in, const int* in_sizes, int n_in,
                              void* d_out, int out_size, void* d_ws, size_t ws_size,
                              hipStream_t stream) {
    const float* user_emb = (const float*)d_in[0];
    const float* item_emb = (const float*)d_in[1];
    const float* gcn_w    = (const float*)d_in[2];
    const float* gcn_b    = (const float*)d_in[3];
    const int*   edges    = (const int*)d_in[4];
    const int*   batch    = (const int*)d_in[5];
    float*       out      = (float*)d_out;

    const size_t NODE_F = (size_t)N_NODES * EMBED;            // 12.8M floats
    float* bufA   = (float*)d_ws;                             // 51.2 MB
    float* bufB   = bufA + NODE_F;                            // 51.2 MB
    float* dinv   = bufB + NODE_F;                            //  2.4 MB
    int*   deg    = (int*)(dinv + M_SEG);                     //  2.4 MB
    int*   excl   = deg + M_SEG;                              //  2.4 MB
    int*   startv = excl + M_SEG;                             //  2.4 MB
    int*   cursor = startv + M_SEG;                           //  2.4 MB
    int*   bsum   = cursor + M_SEG;                           //  16 KB
    int*   srow   = bsum + 4096;                              //  24 MB
    float* loss   = (float*)(srow + (size_t)NB * N_EDGESC);   //   4 B

    hipMemsetAsync(loss, 0, sizeof(float), stream);
    hipMemsetAsync(deg, 0, (size_t)M_SEG * sizeof(int), stream);
    hipMemcpyAsync(bufA, user_emb, (size_t)N_USERS * EMBED * sizeof(float),
                   hipMemcpyDeviceToDevice, stream);
    hipMemcpyAsync(bufA + (size_t)N_USERS * EMBED, item_emb,
                   (size_t)N_ITEMS * EMBED * sizeof(float),
                   hipMemcpyDeviceToDevice, stream);

    // edge preprocessing
    deg_kernel<<<(NB * N_EDGESC + 255) / 256, 256, 0, stream>>>(edges, deg);
    dinv_kernel<<<(M_SEG + 255) / 256, 256, 0, stream>>>(deg, dinv);
    scan1<<<SCAN_BLOCKS, 256, 0, stream>>>(deg, excl, bsum);
    scan2<<<1, 256, 0, stream>>>(bsum, SCAN_BLOCKS);
    scan3<<<SCAN_BLOCKS, 256, 0, stream>>>(excl, bsum, startv, cursor);
    fill_kernel<<<8192, 256, 0, stream>>>(edges, cursor, srow);

    reg_kernel<<<2048, 256, 0, stream>>>(user_emb, item_emb, loss);

    float* cur = bufA;
    float* nxt = bufB;
    for (int bi = 0; bi < NB; ++bi) {
        conv_kernel<<<(N_NODES * 64) / 256, 256, 0, stream>>>(
            srow, startv, deg, dinv, cur,
            gcn_w + (size_t)bi * EMBED * EMBED, gcn_b + bi * EMBED,
            nxt, bi * N_NODES);
        bpr_kernel<<<(BATCH * 64 + 255) / 256, 256, 0, stream>>>(nxt, batch, bi, loss);
        float* t = cur; cur = nxt; nxt = t;
    }
    final_write<<<1, 1, 0, stream>>>(loss, out);
}

// Round 4
// 1053.269 us; speedup vs baseline: 2.3466x; 1.3089x over previous
//
#include <hip/hip_runtime.h>

#define N_USERS  100000
#define N_ITEMS  100000
#define N_NODES  200000
#define EMBED    64
#define NB       3
#define N_EDGESC 2000000
#define NE_TOT   (NB * N_EDGESC)     // 6M
#define BATCH    4096
#define M_SEG    (NB * N_NODES)      // 600000 flat segments
#define NPART    64
#define PSIZE    3125                // N_NODES / NPART (exact)
#define NBUCK    (NB * NPART)        // 192
#define SC_BLOCKS 768
#define SC_ITER   31                 // 768*256*31 = 6,094,848 >= 6M

// ---------------------------------------------------------------- bucket histogram
// per-block LDS hist over 192 (behavior, partition) buckets; 192 global atomics/block
__global__ __launch_bounds__(256) void hist_kernel(const int* __restrict__ edges,
                                                   int* __restrict__ bucketCnt) {
    __shared__ int h[NBUCK];
    for (int i = threadIdx.x; i < NBUCK; i += 256) h[i] = 0;
    __syncthreads();
    int stride = gridDim.x * 256;
    for (int idx = blockIdx.x * 256 + threadIdx.x; idx < NE_TOT; idx += stride) {
        int bi = idx / N_EDGESC;
        int e  = idx - bi * N_EDGESC;
        int c  = edges[((size_t)bi * 2 + 1) * N_EDGESC + e];
        atomicAdd(&h[bi * NPART + c / PSIZE], 1);
    }
    __syncthreads();
    for (int i = threadIdx.x; i < NBUCK; i += 256)
        if (h[i]) atomicAdd(&bucketCnt[i], h[i]);
}

// ---------------------------------------------------------------- scan 192 buckets (1 block)
__global__ __launch_bounds__(256) void scan_buckets(const int* __restrict__ bucketCnt,
                                                    int* __restrict__ bucketBase,
                                                    int* __restrict__ bucketCur,
                                                    int* __restrict__ startv,
                                                    float* __restrict__ loss) {
    __shared__ int s[NBUCK + 1];
    int tid = threadIdx.x;
    if (tid < NBUCK) s[tid] = bucketCnt[tid];
    __syncthreads();
    if (tid == 0) {
        int acc = 0;
        for (int i = 0; i < NBUCK; ++i) { int v = s[i]; s[i] = acc; acc += v; }
        s[NBUCK] = acc;                 // == NE_TOT
        startv[M_SEG] = acc;            // global sentinel for degree-diff
        loss[0] = 0.0f;
    }
    __syncthreads();
    if (tid < NBUCK + 1) bucketBase[tid] = s[tid];
    if (tid < NBUCK)     bucketCur[tid]  = s[tid];
}

// ---------------------------------------------------------------- bucket scatter
// contiguous chunk per block; LDS hist -> one global atomic per bucket -> LDS-cursor append
__global__ __launch_bounds__(256) void bucket_scatter(const int* __restrict__ edges,
                                                      int* __restrict__ bucketCur,
                                                      int* __restrict__ bpack) {
    __shared__ int h[NBUCK];
    __shared__ int lbase[NBUCK];
    for (int i = threadIdx.x; i < NBUCK; i += 256) h[i] = 0;
    __syncthreads();
    int chunk0 = blockIdx.x * (SC_ITER * 256);
    int pk[SC_ITER];
    int pb[SC_ITER];
#pragma unroll
    for (int it = 0; it < SC_ITER; ++it) {
        int idx = chunk0 + it * 256 + threadIdx.x;
        int p = -1, pack = 0;
        if (idx < NE_TOT) {
            int bi = idx / N_EDGESC;
            int e  = idx - bi * N_EDGESC;
            int c  = edges[((size_t)bi * 2 + 1) * N_EDGESC + e];
            int r  = edges[((size_t)bi * 2 + 0) * N_EDGESC + e];
            int pp = c / PSIZE;
            int cl = c - pp * PSIZE;            // < 3125, 12 bits
            p    = bi * NPART + pp;
            pack = (cl << 18) | r;              // r < 200000 < 2^18
            atomicAdd(&h[p], 1);
        }
        pb[it] = p; pk[it] = pack;
    }
    __syncthreads();
    for (int i = threadIdx.x; i < NBUCK; i += 256)
        lbase[i] = h[i] ? atomicAdd(&bucketCur[i], h[i]) : 0;
    __syncthreads();
    for (int i = threadIdx.x; i < NBUCK; i += 256) h[i] = 0;
    __syncthreads();
#pragma unroll
    for (int it = 0; it < SC_ITER; ++it) {
        int p = pb[it];
        if (p >= 0) {
            int pos = lbase[p] + atomicAdd(&h[p], 1);
            bpack[pos] = pk[it];
        }
    }
}

// ---------------------------------------------------------------- place: one block per bucket
// LDS per-col counters -> LDS scan -> write startv/dinv coalesced -> LDS-cursor srow placement
__global__ __launch_bounds__(256) void place_kernel(const int* __restrict__ bpack,
                                                    const int* __restrict__ bucketBase,
                                                    int* __restrict__ startv,
                                                    float* __restrict__ dinv,
                                                    int* __restrict__ srow) {
    __shared__ int cnt[PSIZE + 2];      // counts -> exclusive offsets -> cursors
    __shared__ int tsum[256];
    int b    = blockIdx.x;              // 0..191
    int bi   = b / NPART;
    int part = b - bi * NPART;
    int segBase = bi * N_NODES + part * PSIZE;
    int lo = bucketBase[b], hiEnd = bucketBase[b + 1];

    for (int i = threadIdx.x; i < PSIZE + 1; i += 256) cnt[i] = 0;
    __syncthreads();
    for (int i = lo + threadIdx.x; i < hiEnd; i += 256)
        atomicAdd(&cnt[bpack[i] >> 18], 1);
    __syncthreads();

    // exclusive scan over cnt[0..PSIZE] (sentinel at PSIZE), 13 entries/thread
    int t = threadIdx.x;
    int base0 = t * 13;
    int sum = 0;
#pragma unroll
    for (int k = 0; k < 13; ++k) {
        int i = base0 + k;
        if (i <= PSIZE) sum += cnt[i];
    }
    tsum[t] = sum;
    __syncthreads();
    for (int off = 1; off < 256; off <<= 1) {
        int v = (t >= off) ? tsum[t - off] : 0;
        __syncthreads();
        tsum[t] += v;
        __syncthreads();
    }
    int run = tsum[t] - sum;
    int vals[13];
#pragma unroll
    for (int k = 0; k < 13; ++k) {
        int i = base0 + k;
        vals[k] = (i <= PSIZE) ? cnt[i] : 0;
    }
    __syncthreads();
#pragma unroll
    for (int k = 0; k < 13; ++k) {
        int i = base0 + k;
        if (i <= PSIZE) { cnt[i] = run; run += vals[k]; }
    }
    __syncthreads();

    // startv / dinv, coalesced
    for (int i = threadIdx.x; i < PSIZE; i += 256) {
        int excl = cnt[i];
        int d    = cnt[i + 1] - excl;
        startv[segBase + i] = lo + excl;
        dinv[segBase + i]   = (d > 0) ? rsqrtf((float)d) : 0.0f;
    }
    __syncthreads();

    // place rows via LDS cursors; srow slice [lo, hiEnd) is exclusive to this block
    for (int i = lo + threadIdx.x; i < hiEnd; i += 256) {
        int pk  = bpack[i];
        int pos = atomicAdd(&cnt[pk >> 18], 1);
        srow[lo + pos] = pk & 0x3FFFF;
    }
}

// ---------------------------------------------------------------- fused conv:
// gather-accumulate raw total rows + @W (LDS) + bias + l2norm + residual
__global__ __launch_bounds__(256) void conv_kernel(const int* __restrict__ srow,
                                                   const int* __restrict__ startv,
                                                   const float* __restrict__ dinv,
                                                   const float* __restrict__ tin,
                                                   const float* __restrict__ W,
                                                   const float* __restrict__ bias,
                                                   float* __restrict__ tout,
                                                   int base /* bi*N_NODES */) {
    __shared__ float sW[64 * 64];
    __shared__ float sAcc[4][64];
    for (int i = threadIdx.x; i < 1024; i += 256)
        ((float4*)sW)[i] = ((const float4*)W)[i];
    __syncthreads();

    int gid  = blockIdx.x * 256 + threadIdx.x;   // grid exactly N_NODES*64
    int c    = gid >> 6;
    int wv   = threadIdx.x >> 6;
    int lane = threadIdx.x & 63;

    int   s   = startv[base + c];
    int   end = startv[base + c + 1];
    float dc  = dinv[base + c];
    float acc = 0.0f;
    int e = s;
    for (; e + 4 <= end; e += 4) {
        int r0 = srow[e], r1 = srow[e + 1], r2 = srow[e + 2], r3 = srow[e + 3];
        float n0 = dinv[base + r0], n1 = dinv[base + r1];
        float n2 = dinv[base + r2], n3 = dinv[base + r3];
        float v0 = tin[(size_t)r0 * 64 + lane];
        float v1 = tin[(size_t)r1 * 64 + lane];
        float v2 = tin[(size_t)r2 * 64 + lane];
        float v3 = tin[(size_t)r3 * 64 + lane];
        acc += n0 * v0 + n1 * v1 + n2 * v2 + n3 * v3;
    }
    for (; e < end; ++e) {
        int r = srow[e];
        acc += dinv[base + r] * tin[(size_t)r * 64 + lane];
    }
    sAcc[wv][lane] = acc;
    float v = 0.0f;
#pragma unroll
    for (int k = 0; k < 64; ++k)
        v += sAcc[wv][k] * sW[k * 64 + lane];
    v = v * dc + bias[lane];
    float sq = v * v;
#pragma unroll
    for (int off = 32; off; off >>= 1) sq += __shfl_xor(sq, off, 64);
    float inv = 1.0f / fmaxf(sqrtf(sq), 1e-12f);
    size_t idx = (size_t)c * 64 + lane;
    tout[idx] = tin[idx] + v * inv;
}

// ---------------------------------------------------------------- BPR loss
__global__ __launch_bounds__(256) void bpr_kernel(const float* __restrict__ total,
                                                  const int* __restrict__ batch,
                                                  int bi, float* __restrict__ loss) {
    int gid  = blockIdx.x * 256 + threadIdx.x;
    int b    = gid >> 6;
    int lane = threadIdx.x & 63;
    if (b >= BATCH) return;
    int u  = batch[((size_t)b * NB + bi) * 3 + 0];
    int i0 = batch[((size_t)b * NB + bi) * 3 + 1];
    int i1 = batch[((size_t)b * NB + bi) * 3 + 2];
    float uf = total[(size_t)u * 64 + lane];
    float f0 = total[(size_t)(N_USERS + i0) * 64 + lane];
    float f1 = total[(size_t)(N_USERS + i1) * 64 + lane];
    float d  = uf * (f0 - f1);
#pragma unroll
    for (int off = 32; off; off >>= 1) d += __shfl_xor(d, off, 64);
    if (lane == 0) {
        float sp = (d > 0.0f) ? log1pf(expf(-d)) : (-d + log1pf(expf(d)));
        unsafeAtomicAdd(loss, sp * (1.0f / BATCH));
    }
}

// ---------------------------------------------------------------- embedding L2 reg
__global__ __launch_bounds__(256) void reg_kernel(const float* __restrict__ ue,
                                                  const float* __restrict__ ie,
                                                  float* __restrict__ loss) {
    const size_t n4 = (size_t)N_USERS * EMBED / 4;
    size_t tid    = (size_t)blockIdx.x * 256 + threadIdx.x;
    size_t stride = (size_t)gridDim.x * 256;
    const float4* u4 = (const float4*)ue;
    const float4* i4 = (const float4*)ie;
    float s = 0.0f;
    for (size_t i = tid; i < n4; i += stride) {
        float4 a = u4[i];
        s += a.x * a.x + a.y * a.y + a.z * a.z + a.w * a.w;
        float4 b = i4[i];
        s += b.x * b.x + b.y * b.y + b.z * b.z + b.w * b.w;
    }
#pragma unroll
    for (int off = 32; off; off >>= 1) s += __shfl_xor(s, off, 64);
    if ((threadIdx.x & 63) == 0)
        unsafeAtomicAdd(loss, s * (0.5f * 0.0001f / (float)BATCH));
}

// ---------------------------------------------------------------- final scalar write
__global__ void final_write(const float* __restrict__ loss, float* __restrict__ out) {
    out[0] = loss[0];
}

extern "C" void kernel_launch(void* const* d_in, const int* in_sizes, int n_in,
                              void* d_out, int out_size, void* d_ws, size_t ws_size,
                              hipStream_t stream) {
    const float* user_emb = (const float*)d_in[0];
    const float* item_emb = (const float*)d_in[1];
    const float* gcn_w    = (const float*)d_in[2];
    const float* gcn_b    = (const float*)d_in[3];
    const int*   edges    = (const int*)d_in[4];
    const int*   batch    = (const int*)d_in[5];
    float*       out      = (float*)d_out;

    const size_t NODE_F = (size_t)N_NODES * EMBED;            // 12.8M floats
    float* bufA    = (float*)d_ws;                            // 51.2 MB
    float* bufB    = bufA + NODE_F;                           // 51.2 MB
    float* dinv    = bufB + NODE_F;                           //  2.4 MB
    int*   startv  = (int*)(dinv + M_SEG);                    //  2.4 MB (+1 sentinel)
    int*   bCnt    = startv + M_SEG + 1;                      //  768 B
    int*   bBase   = bCnt + NBUCK;                            //  772 B
    int*   bCur    = bBase + NBUCK + 1;                       //  768 B
    int*   bpack   = bCur + NBUCK;                            //  24 MB
    int*   srow    = bpack + NE_TOT;                          //  24 MB
    float* loss    = (float*)(srow + NE_TOT);                 //   4 B

    hipMemsetAsync(bCnt, 0, NBUCK * sizeof(int), stream);
    hipMemcpyAsync(bufA, user_emb, (size_t)N_USERS * EMBED * sizeof(float),
                   hipMemcpyDeviceToDevice, stream);
    hipMemcpyAsync(bufA + (size_t)N_USERS * EMBED, item_emb,
                   (size_t)N_ITEMS * EMBED * sizeof(float),
                   hipMemcpyDeviceToDevice, stream);

    // counting sort by destination column (two-pass, LDS-aggregated)
    hist_kernel<<<768, 256, 0, stream>>>(edges, bCnt);
    scan_buckets<<<1, 256, 0, stream>>>(bCnt, bBase, bCur, startv, loss);
    bucket_scatter<<<SC_BLOCKS, 256, 0, stream>>>(edges, bCur, bpack);
    place_kernel<<<NBUCK, 256, 0, stream>>>(bpack, bBase, startv, dinv, srow);

    reg_kernel<<<2048, 256, 0, stream>>>(user_emb, item_emb, loss);

    float* cur = bufA;
    float* nxt = bufB;
    for (int bi = 0; bi < NB; ++bi) {
        conv_kernel<<<(N_NODES * 64) / 256, 256, 0, stream>>>(
            srow, startv, dinv, cur,
            gcn_w + (size_t)bi * EMBED * EMBED, gcn_b + bi * EMBED,
            nxt, bi * N_NODES);
        bpr_kernel<<<(BATCH * 64 + 255) / 256, 256, 0, stream>>>(nxt, batch, bi, loss);
        float* t = cur; cur = nxt; nxt = t;
    }
    final_write<<<1, 1, 0, stream>>>(loss, out);
}

// Round 5
// 1023.486 us; speedup vs baseline: 2.4149x; 1.0291x over previous
//
#include <hip/hip_runtime.h>

#define N_USERS  100000
#define N_ITEMS  100000
#define N_NODES  200000
#define EMBED    64
#define NB       3
#define N_EDGESC 2000000
#define NE_TOT   (NB * N_EDGESC)     // 6M
#define BATCH    4096
#define M_SEG    (NB * N_NODES)      // 600000 flat segments
#define NPART    64
#define PSIZE    3125                // N_NODES / NPART (exact)
#define NBUCK    (NB * NPART)        // 192
#define SC_ITER  16                  // 512 blk/behavior * 256 * 16 = 2,097,152 >= 2M
#define CONV_BLOCKS 2048
#define NPW      25                  // nodes per wave: 2048*4*25 = 204800 >= 200000

// ---------------------------------------------------------------- bucket histogram
// 256 blocks per behavior; per-block LDS hist over 64 partitions
__global__ __launch_bounds__(256) void hist_kernel(const int* __restrict__ edges,
                                                   int* __restrict__ bucketCnt) {
    __shared__ int h[NPART];
    int bi = blockIdx.x >> 8;                    // 768 blocks total
    const int* cols = edges + ((size_t)bi * 2 + 1) * N_EDGESC;
    if (threadIdx.x < NPART) h[threadIdx.x] = 0;
    __syncthreads();
    int stride = 256 * 256;
    for (int idx = (blockIdx.x & 255) * 256 + threadIdx.x; idx < N_EDGESC; idx += stride)
        atomicAdd(&h[cols[idx] / PSIZE], 1);
    __syncthreads();
    if (threadIdx.x < NPART && h[threadIdx.x])
        atomicAdd(&bucketCnt[bi * NPART + threadIdx.x], h[threadIdx.x]);
}

// ---------------------------------------------------------------- scan 192 buckets (1 block)
__global__ __launch_bounds__(256) void scan_buckets(const int* __restrict__ bucketCnt,
                                                    int* __restrict__ bucketBase,
                                                    int* __restrict__ bucketCur,
                                                    int* __restrict__ startv,
                                                    float* __restrict__ loss) {
    __shared__ int s[NBUCK + 1];
    int tid = threadIdx.x;
    if (tid < NBUCK) s[tid] = bucketCnt[tid];
    __syncthreads();
    if (tid == 0) {
        int acc = 0;
        for (int i = 0; i < NBUCK; ++i) { int v = s[i]; s[i] = acc; acc += v; }
        s[NBUCK] = acc;                 // == NE_TOT
        startv[M_SEG] = acc;            // sentinel for degree-diff
        loss[0] = 0.0f;
    }
    __syncthreads();
    if (tid < NBUCK + 1) bucketBase[tid] = s[tid];
    if (tid < NBUCK)     bucketCur[tid]  = s[tid];
}

// ---------------------------------------------------------------- bucket scatter
// 512 blocks per behavior, contiguous 4096-edge chunk each;
// LDS hist -> one global atomic per partition -> LDS-cursor append
__global__ __launch_bounds__(256) void bucket_scatter(const int* __restrict__ edges,
                                                      int* __restrict__ bucketCur,
                                                      int* __restrict__ bpack) {
    __shared__ int h[NPART];
    __shared__ int lbase[NPART];
    int bi  = blockIdx.x >> 9;                   // 1536 blocks total
    int blk = blockIdx.x & 511;
    const int* rows = edges + ((size_t)bi * 2 + 0) * N_EDGESC;
    const int* cols = edges + ((size_t)bi * 2 + 1) * N_EDGESC;
    if (threadIdx.x < NPART) h[threadIdx.x] = 0;
    __syncthreads();
    int base0 = blk * (SC_ITER * 256);
    int pk[SC_ITER];
    int pp[SC_ITER];
#pragma unroll
    for (int it = 0; it < SC_ITER; ++it) {
        int idx = base0 + it * 256 + threadIdx.x;
        int p = -1, pack = 0;
        if (idx < N_EDGESC) {
            int c  = cols[idx];
            int r  = rows[idx];
            p      = c / PSIZE;
            pack   = ((c - p * PSIZE) << 18) | r;   // cl<12b><<18 | r<2^18
            atomicAdd(&h[p], 1);
        }
        pp[it] = p; pk[it] = pack;
    }
    __syncthreads();
    if (threadIdx.x < NPART)
        lbase[threadIdx.x] = h[threadIdx.x]
            ? atomicAdd(&bucketCur[bi * NPART + threadIdx.x], h[threadIdx.x]) : 0;
    __syncthreads();
    if (threadIdx.x < NPART) h[threadIdx.x] = 0;
    __syncthreads();
#pragma unroll
    for (int it = 0; it < SC_ITER; ++it) {
        int p = pp[it];
        if (p >= 0) {
            int pos = lbase[p] + atomicAdd(&h[p], 1);
            bpack[pos] = pk[it];
        }
    }
}

// ---------------------------------------------------------------- place: one block per bucket
__global__ __launch_bounds__(256) void place_kernel(const int* __restrict__ bpack,
                                                    const int* __restrict__ bucketBase,
                                                    int* __restrict__ startv,
                                                    float* __restrict__ dinv,
                                                    int* __restrict__ srow) {
    __shared__ int cnt[PSIZE + 2];
    __shared__ int tsum[256];
    int b    = blockIdx.x;              // 0..191
    int bi   = b / NPART;
    int part = b - bi * NPART;
    int segBase = bi * N_NODES + part * PSIZE;
    int lo = bucketBase[b], hiEnd = bucketBase[b + 1];

    for (int i = threadIdx.x; i < PSIZE + 1; i += 256) cnt[i] = 0;
    __syncthreads();
    for (int i = lo + threadIdx.x; i < hiEnd; i += 256)
        atomicAdd(&cnt[bpack[i] >> 18], 1);
    __syncthreads();

    int t = threadIdx.x;
    int base0 = t * 13;
    int sum = 0;
#pragma unroll
    for (int k = 0; k < 13; ++k) {
        int i = base0 + k;
        if (i <= PSIZE) sum += cnt[i];
    }
    tsum[t] = sum;
    __syncthreads();
    for (int off = 1; off < 256; off <<= 1) {
        int v = (t >= off) ? tsum[t - off] : 0;
        __syncthreads();
        tsum[t] += v;
        __syncthreads();
    }
    int run = tsum[t] - sum;
    int vals[13];
#pragma unroll
    for (int k = 0; k < 13; ++k) {
        int i = base0 + k;
        vals[k] = (i <= PSIZE) ? cnt[i] : 0;
    }
    __syncthreads();
#pragma unroll
    for (int k = 0; k < 13; ++k) {
        int i = base0 + k;
        if (i <= PSIZE) { cnt[i] = run; run += vals[k]; }
    }
    __syncthreads();

    for (int i = threadIdx.x; i < PSIZE; i += 256) {
        int excl = cnt[i];
        int d    = cnt[i + 1] - excl;
        startv[segBase + i] = lo + excl;
        dinv[segBase + i]   = (d > 0) ? rsqrtf((float)d) : 0.0f;
    }
    __syncthreads();

    for (int i = lo + threadIdx.x; i < hiEnd; i += 256) {
        int pk  = bpack[i];
        int pos = atomicAdd(&cnt[pk >> 18], 1);
        srow[lo + pos] = pk & 0x3FFFF;
    }
}

// ---------------------------------------------------------------- fused conv v2:
// wave owns 25 contiguous nodes. W column in 64 VGPRs per lane (loaded once).
// Gather: 4 subgroups x 16 lanes, float4 rows, 8 edges in flight.
// Dot via readlane broadcast (no LDS at all). Fused bias+l2norm+residual.
__global__ __launch_bounds__(256) void conv_kernel(const int* __restrict__ srow,
                                                   const int* __restrict__ startv,
                                                   const float* __restrict__ dinv,
                                                   const float* __restrict__ tin,
                                                   const float* __restrict__ W,
                                                   const float* __restrict__ bias,
                                                   float* __restrict__ tout,
                                                   int base /* bi*N_NODES */) {
    int lane = threadIdx.x & 63;
    int sub  = lane >> 4;        // 0..3 (edge slot)
    int li   = lane & 15;        // 0..15 (float4 slot)
    float w[64];
#pragma unroll
    for (int k = 0; k < 64; ++k) w[k] = W[k * 64 + lane];
    float bs = bias[lane];
    int wgid = blockIdx.x * 4 + (threadIdx.x >> 6);
    int c0 = wgid * NPW;
    int c1 = c0 + NPW; if (c1 > N_NODES) c1 = N_NODES;
    const float4* tin4 = (const float4*)tin;

    for (int c = c0; c < c1; ++c) {
        int   s   = startv[base + c];
        int   end = startv[base + c + 1];
        float dc  = dinv[base + c];
        float4 accA = {0.f, 0.f, 0.f, 0.f};
        float4 accB = {0.f, 0.f, 0.f, 0.f};
        int e = s;
        for (; e + 8 <= end; e += 8) {
            int r0 = srow[e + sub];
            int r1 = srow[e + 4 + sub];
            float n0 = dinv[base + r0];
            float n1 = dinv[base + r1];
            float4 v0 = tin4[(size_t)r0 * 16 + li];
            float4 v1 = tin4[(size_t)r1 * 16 + li];
            accA.x += n0 * v0.x; accA.y += n0 * v0.y;
            accA.z += n0 * v0.z; accA.w += n0 * v0.w;
            accB.x += n1 * v1.x; accB.y += n1 * v1.y;
            accB.z += n1 * v1.z; accB.w += n1 * v1.w;
        }
        for (; e < end; e += 4) {
            int  ei  = e + sub;
            bool ok  = ei < end;
            int  eic = ok ? ei : e;          // e < end, always valid
            int  r   = srow[eic];
            float n  = ok ? dinv[base + r] : 0.0f;
            float4 v = tin4[(size_t)r * 16 + li];
            accA.x += n * v.x; accA.y += n * v.y;
            accA.z += n * v.z; accA.w += n * v.w;
        }
        float4 acc;
        acc.x = accA.x + accB.x; acc.y = accA.y + accB.y;
        acc.z = accA.z + accB.z; acc.w = accA.w + accB.w;
        // combine the 4 edge-subgroups: lanes l, l^16, l^32, l^48 share dims
        acc.x += __shfl_xor(acc.x, 16, 64); acc.y += __shfl_xor(acc.y, 16, 64);
        acc.z += __shfl_xor(acc.z, 16, 64); acc.w += __shfl_xor(acc.w, 16, 64);
        acc.x += __shfl_xor(acc.x, 32, 64); acc.y += __shfl_xor(acc.y, 32, 64);
        acc.z += __shfl_xor(acc.z, 32, 64); acc.w += __shfl_xor(acc.w, 32, 64);
        // dot: v_lane = sum_k acc[k] * W[k][lane]; acc[4q+c] lives at lane q, comp c
        float p0 = 0.f, p1 = 0.f, p2 = 0.f, p3 = 0.f;
#pragma unroll
        for (int q = 0; q < 16; ++q) {
            float a0 = __int_as_float(__builtin_amdgcn_readlane(__float_as_int(acc.x), q));
            float a1 = __int_as_float(__builtin_amdgcn_readlane(__float_as_int(acc.y), q));
            float a2 = __int_as_float(__builtin_amdgcn_readlane(__float_as_int(acc.z), q));
            float a3 = __int_as_float(__builtin_amdgcn_readlane(__float_as_int(acc.w), q));
            p0 += a0 * w[4 * q + 0];
            p1 += a1 * w[4 * q + 1];
            p2 += a2 * w[4 * q + 2];
            p3 += a3 * w[4 * q + 3];
        }
        float v = (p0 + p1) + (p2 + p3);
        v = v * dc + bs;
        float sq = v * v;
#pragma unroll
        for (int off = 32; off; off >>= 1) sq += __shfl_xor(sq, off, 64);
        float inv = 1.0f / fmaxf(sqrtf(sq), 1e-12f);
        size_t idx = (size_t)c * 64 + lane;
        tout[idx] = tin[idx] + v * inv;
    }
}

// ---------------------------------------------------------------- BPR loss
__global__ __launch_bounds__(256) void bpr_kernel(const float* __restrict__ total,
                                                  const int* __restrict__ batch,
                                                  int bi, float* __restrict__ loss) {
    int gid  = blockIdx.x * 256 + threadIdx.x;
    int b    = gid >> 6;
    int lane = threadIdx.x & 63;
    if (b >= BATCH) return;
    int u  = batch[((size_t)b * NB + bi) * 3 + 0];
    int i0 = batch[((size_t)b * NB + bi) * 3 + 1];
    int i1 = batch[((size_t)b * NB + bi) * 3 + 2];
    float uf = total[(size_t)u * 64 + lane];
    float f0 = total[(size_t)(N_USERS + i0) * 64 + lane];
    float f1 = total[(size_t)(N_USERS + i1) * 64 + lane];
    float d  = uf * (f0 - f1);
#pragma unroll
    for (int off = 32; off; off >>= 1) d += __shfl_xor(d, off, 64);
    if (lane == 0) {
        float sp = (d > 0.0f) ? log1pf(expf(-d)) : (-d + log1pf(expf(d)));
        unsafeAtomicAdd(loss, sp * (1.0f / BATCH));
    }
}

// ---------------------------------------------------------------- embedding L2 reg
__global__ __launch_bounds__(256) void reg_kernel(const float* __restrict__ ue,
                                                  const float* __restrict__ ie,
                                                  float* __restrict__ loss) {
    const size_t n4 = (size_t)N_USERS * EMBED / 4;
    size_t tid    = (size_t)blockIdx.x * 256 + threadIdx.x;
    size_t stride = (size_t)gridDim.x * 256;
    const float4* u4 = (const float4*)ue;
    const float4* i4 = (const float4*)ie;
    float s = 0.0f;
    for (size_t i = tid; i < n4; i += stride) {
        float4 a = u4[i];
        s += a.x * a.x + a.y * a.y + a.z * a.z + a.w * a.w;
        float4 b = i4[i];
        s += b.x * b.x + b.y * b.y + b.z * b.z + b.w * b.w;
    }
#pragma unroll
    for (int off = 32; off; off >>= 1) s += __shfl_xor(s, off, 64);
    if ((threadIdx.x & 63) == 0)
        unsafeAtomicAdd(loss, s * (0.5f * 0.0001f / (float)BATCH));
}

// ---------------------------------------------------------------- final scalar write
__global__ void final_write(const float* __restrict__ loss, float* __restrict__ out) {
    out[0] = loss[0];
}

extern "C" void kernel_launch(void* const* d_in, const int* in_sizes, int n_in,
                              void* d_out, int out_size, void* d_ws, size_t ws_size,
                              hipStream_t stream) {
    const float* user_emb = (const float*)d_in[0];
    const float* item_emb = (const float*)d_in[1];
    const float* gcn_w    = (const float*)d_in[2];
    const float* gcn_b    = (const float*)d_in[3];
    const int*   edges    = (const int*)d_in[4];
    const int*   batch    = (const int*)d_in[5];
    float*       out      = (float*)d_out;

    const size_t NODE_F = (size_t)N_NODES * EMBED;            // 12.8M floats
    float* bufA    = (float*)d_ws;                            // 51.2 MB
    float* bufB    = bufA + NODE_F;                           // 51.2 MB
    float* dinv    = bufB + NODE_F;                           //  2.4 MB
    int*   startv  = (int*)(dinv + M_SEG);                    //  2.4 MB (+1 sentinel)
    int*   bCnt    = startv + M_SEG + 1;                      //  768 B
    int*   bBase   = bCnt + NBUCK;                            //  772 B
    int*   bCur    = bBase + NBUCK + 1;                       //  768 B
    int*   bpack   = bCur + NBUCK;                            //  24 MB
    int*   srow    = bpack + NE_TOT;                          //  24 MB
    float* loss    = (float*)(srow + NE_TOT);                 //   4 B

    hipMemsetAsync(bCnt, 0, NBUCK * sizeof(int), stream);
    hipMemcpyAsync(bufA, user_emb, (size_t)N_USERS * EMBED * sizeof(float),
                   hipMemcpyDeviceToDevice, stream);
    hipMemcpyAsync(bufA + (size_t)N_USERS * EMBED, item_emb,
                   (size_t)N_ITEMS * EMBED * sizeof(float),
                   hipMemcpyDeviceToDevice, stream);

    // counting sort by destination column (two-pass, LDS-aggregated)
    hist_kernel<<<NB * 256, 256, 0, stream>>>(edges, bCnt);
    scan_buckets<<<1, 256, 0, stream>>>(bCnt, bBase, bCur, startv, loss);
    bucket_scatter<<<NB * 512, 256, 0, stream>>>(edges, bCur, bpack);
    place_kernel<<<NBUCK, 256, 0, stream>>>(bpack, bBase, startv, dinv, srow);

    reg_kernel<<<2048, 256, 0, stream>>>(user_emb, item_emb, loss);

    float* cur = bufA;
    float* nxt = bufB;
    for (int bi = 0; bi < NB; ++bi) {
        conv_kernel<<<CONV_BLOCKS, 256, 0, stream>>>(
            srow, startv, dinv, cur,
            gcn_w + (size_t)bi * EMBED * EMBED, gcn_b + bi * EMBED,
            nxt, bi * N_NODES);
        bpr_kernel<<<(BATCH * 64 + 255) / 256, 256, 0, stream>>>(nxt, batch, bi, loss);
        float* t = cur; cur = nxt; nxt = t;
    }
    final_write<<<1, 1, 0, stream>>>(loss, out);
}